// Round 6
// baseline (33846.536 us; speedup 1.0000x reference)
//
#include <hip/hip_runtime.h>
#include <hip/hip_cooperative_groups.h>

namespace cg = cooperative_groups;

#define NB 64
#define NT 256
#define ND 1024
#define NH 1024
#define G4 4096

typedef _Float16 half_t;
typedef half_t v8h __attribute__((ext_vector_type(8)));
typedef half_t h4  __attribute__((ext_vector_type(4)));
typedef float  v4f __attribute__((ext_vector_type(4)));

#define XPLANE ((size_t)NB * NT * ND)   // 16,777,216 elems per x plane
#define HPLANE ((size_t)NB * NH)        // 65,536 elems per h plane
#define WREG   16384                    // halves per (combo,jp,gt,kh) region (32 KB)

// ---- one-time: x (B,T,D) f32 -> fp16 hi/lo planes, transposed to [t][b][d] ----
__global__ void cvt_x(const float* __restrict__ x,
                      half_t* __restrict__ xh, half_t* __restrict__ xl) {
    const int row = blockIdx.x;             // row = b*256 + t, 16384 rows
    const int b = row >> 8, t = row & 255;
    const int o = threadIdx.x * 4;          // 256 threads * 4 = 1024
    const float4 v = *(const float4*)(x + (size_t)row * ND + o);
    const size_t d = ((size_t)t * NB + b) * ND + o;
    h4 hh, ll;
    hh.x = (half_t)v.x; ll.x = (half_t)(v.x - (float)hh.x);
    hh.y = (half_t)v.y; ll.y = (half_t)(v.y - (float)hh.y);
    hh.z = (half_t)v.z; ll.z = (half_t)(v.z - (float)hh.z);
    hh.w = (half_t)v.w; ll.w = (half_t)(v.w - (float)hh.w);
    *(h4*)(xh + d) = hh;
    *(h4*)(xl + d) = ll;
}

// ---- one-time weight pack: fp16, region per (combo,jp,gt,kh): [kk 0..31][lane][8] ----
// combo: 0=fw L0, 1=bw L0, 2=fw L1, 3=bw L1;  kh: 0 = Wx, 1 = Wh
__global__ void transpose_pack(const float* __restrict__ fw_Wx,
                               const float* __restrict__ fw_Wh,
                               const float* __restrict__ bw_Wx,
                               const float* __restrict__ bw_Wh,
                               half_t* __restrict__ WT) {
    const int z = blockIdx.z;
    const int combo = z >> 1;
    const int half  = z & 1;               // 0 -> Wx, 1 -> Wh (== kh)
    const int layer = combo >> 1, dirb = combo & 1;
    const float* src = half ? (dirb ? bw_Wh : fw_Wh) : (dirb ? bw_Wx : fw_Wx);
    src += (size_t)layer * ND * G4;
    const int n0 = blockIdx.x * 64, k0 = blockIdx.y * 64;
    __shared__ float tile[64][65];
    const int t = threadIdx.x;             // 256 threads
    #pragma unroll
    for (int it = 0; it < 4; ++it) {
        const int kr = it * 16 + (t >> 4);
        const int nc = (t & 15) * 4;
        const float4 v = *(const float4*)(src + (size_t)(k0 + kr) * G4 + n0 + nc);
        tile[kr][nc + 0] = v.x; tile[kr][nc + 1] = v.y;
        tile[kr][nc + 2] = v.z; tile[kr][nc + 3] = v.w;
    }
    __syncthreads();
    #pragma unroll
    for (int it = 0; it < 4; ++it) {
        const int nr = it * 16 + (t >> 4);
        const int kc = (t & 15) * 4;       // k within tile, multiple of 4
        h4 hv;
        hv.x = (half_t)tile[kc + 0][nr];
        hv.y = (half_t)tile[kc + 1][nr];
        hv.z = (half_t)tile[kc + 2][nr];
        hv.w = (half_t)tile[kc + 3][nr];
        const int n = n0 + nr;                 // 0..4095
        const int k1 = k0 + kc;                // 0..1023 within this kh
        const int gt = n >> 10, j = n & 1023;
        const int jp = j >> 4, l15 = j & 15;
        const int kk = k1 >> 5, g = (k1 >> 3) & 3, e0 = k1 & 7;  // e0 in {0,4}
        const int lane = g * 16 + l15;
        const size_t r = (((size_t)combo * 64 + jp) * 4 + gt) * 2 + half;
        *(h4*)(WT + r * WREG + (size_t)kk * 512 + lane * 8 + e0) = hv;
    }
}

// ---- persistent scan kernel: block = (combo, j-panel); 8 waves = (gate, K-half) ----
// hbuf layout: [combo][parity][plane hi/lo][B][H] fp16
__global__ __launch_bounds__(512, 2) void lstm_persistent(
        const half_t* __restrict__ xh, const half_t* __restrict__ xl,
        const int* __restrict__ lengths,
        const float* __restrict__ fw_b, const float* __restrict__ bw_b,
        const half_t* __restrict__ WT,
        half_t* __restrict__ hbuf,
        float* __restrict__ out) {
    const int c = blockIdx.x & 3, jp = blockIdx.x >> 2;
    const int layer = c >> 1, dir = c & 1;
    const int tid = threadIdx.x;
    const int wv = tid >> 6, lane = tid & 63;
    const int gt = wv & 3, kh = wv >> 2;
    const int l15 = lane & 15, g = lane >> 4;
    const int j0 = jp * 16;

    __shared__ float glds[4][2][NB][16];   // [gate][kh][batch][jj]
    __shared__ float c_lds[NB][16];
    __shared__ float h_lds[NB][16];
    __shared__ float bias_lds[4][16];
    __shared__ int   len_lds[NB];

    for (int e = tid; e < NB * 16; e += 512) {
        c_lds[e >> 4][e & 15] = 0.f;
        h_lds[e >> 4][e & 15] = 0.f;
    }
    if (tid < NB) len_lds[tid] = lengths[tid];
    if (tid < 64) {
        const int gg = tid >> 4, jj = tid & 15;
        const float* bs = dir ? bw_b : fw_b;
        bias_lds[gg][jj] = bs[(size_t)layer * G4 + gg * NH + j0 + jj];
    }

    // ---- W preload: whole scan's weights live in registers ----
    v8h w[32];
    {
        const half_t* wp = WT + ((((size_t)c * 64 + jp) * 4 + gt) * 2 + kh) * WREG
                         + (size_t)lane * 8;
        #pragma unroll
        for (int kk = 0; kk < 32; ++kk) w[kk] = *(const v8h*)(wp + (size_t)kk * 512);
    }
    __syncthreads();

    cg::grid_group grid = cg::this_grid();

    for (int s = 0; s <= NT; ++s) {
        const bool active = (layer == 0) ? (s < NT) : (s >= 1);
        const int u = (layer == 0) ? s : (s - 1);

        if (active) {
            // A source pointers (fp16 hi/lo), rows = batch, row stride = 1024
            const half_t *pah, *pal;
            if (kh == 0) {
                if (layer == 0) {
                    const int t = dir ? (NT - 1 - u) : u;
                    const size_t o = ((size_t)t * NB + l15) * ND + g * 8;
                    pah = xh + o; pal = xl + o;
                } else {
                    const half_t* hb = hbuf + (((size_t)dir * 2 + (s & 1)) * 2) * HPLANE;
                    pah = hb + (size_t)l15 * NH + g * 8; pal = pah + HPLANE;
                }
            } else {
                const half_t* hb = hbuf + (((size_t)c * 2 + (u & 1)) * 2) * HPLANE;
                pah = hb + (size_t)l15 * NH + g * 8; pal = pah + HPLANE;
            }

            v4f acc0 = {0.f,0.f,0.f,0.f}, acc1 = acc0, acc2 = acc0, acc3 = acc0;
            #pragma unroll
            for (int kk = 0; kk < 32; ++kk) {
                const int ko = kk * 32;
                v8h a, b;
                a = *(const v8h*)(pah + ko);
                b = *(const v8h*)(pal + ko);
                acc0 = __builtin_amdgcn_mfma_f32_16x16x32_f16(a, w[kk], acc0, 0, 0, 0);
                acc0 = __builtin_amdgcn_mfma_f32_16x16x32_f16(b, w[kk], acc0, 0, 0, 0);
                a = *(const v8h*)(pah + 16384 + ko);
                b = *(const v8h*)(pal + 16384 + ko);
                acc1 = __builtin_amdgcn_mfma_f32_16x16x32_f16(a, w[kk], acc1, 0, 0, 0);
                acc1 = __builtin_amdgcn_mfma_f32_16x16x32_f16(b, w[kk], acc1, 0, 0, 0);
                a = *(const v8h*)(pah + 32768 + ko);
                b = *(const v8h*)(pal + 32768 + ko);
                acc2 = __builtin_amdgcn_mfma_f32_16x16x32_f16(a, w[kk], acc2, 0, 0, 0);
                acc2 = __builtin_amdgcn_mfma_f32_16x16x32_f16(b, w[kk], acc2, 0, 0, 0);
                a = *(const v8h*)(pah + 49152 + ko);
                b = *(const v8h*)(pal + 49152 + ko);
                acc3 = __builtin_amdgcn_mfma_f32_16x16x32_f16(a, w[kk], acc3, 0, 0, 0);
                acc3 = __builtin_amdgcn_mfma_f32_16x16x32_f16(b, w[kk], acc3, 0, 0, 0);
            }
            // C/D: col = lane&15 (jj), row-in-tile = g*4 + r
            #pragma unroll
            for (int r = 0; r < 4; ++r) {
                glds[gt][kh][ 0 + g * 4 + r][l15] = acc0[r];
                glds[gt][kh][16 + g * 4 + r][l15] = acc1[r];
                glds[gt][kh][32 + g * 4 + r][l15] = acc2[r];
                glds[gt][kh][48 + g * 4 + r][l15] = acc3[r];
            }
        }
        __syncthreads();

        if (active) {
            for (int e = tid; e < NB * 16; e += 512) {
                const int b = e >> 4, jj = e & 15;
                const float iv = glds[0][0][b][jj] + glds[0][1][b][jj] + bias_lds[0][jj];
                const float fv = glds[1][0][b][jj] + glds[1][1][b][jj] + bias_lds[1][jj];
                const float gv = glds[2][0][b][jj] + glds[2][1][b][jj] + bias_lds[2][jj];
                const float ov = glds[3][0][b][jj] + glds[3][1][b][jj] + bias_lds[3][jj];
                const float cold = c_lds[b][jj];
                const float hold = h_lds[b][jj];
                const float si = 1.f / (1.f + expf(-iv));
                const float sf = 1.f / (1.f + expf(-fv));
                const float so = 1.f / (1.f + expf(-ov));
                const float cn = sf * cold + si * tanhf(gv);
                const float hn = so * tanhf(cn);
                const bool valid = len_lds[b] > u;   // un-reversed mask (reference quirk)
                const float c2 = valid ? cn : cold;
                const float h2 = valid ? hn : hold;
                c_lds[b][jj] = c2;
                h_lds[b][jj] = h2;
                const size_t hb = (((size_t)c * 2 + ((u + 1) & 1)) * 2) * HPLANE
                                + (size_t)b * NH + j0 + jj;
                const half_t hh = (half_t)h2;
                hbuf[hb]          = hh;
                hbuf[hb + HPLANE] = (half_t)(h2 - (float)hh);
                if (layer == 1) {
                    const int tout = dir ? (NT - 1 - u) : u;
                    out[((size_t)b * NT + tout) * (2 * NH) + dir * NH + j0 + jj] = h2;
                    if (u == NT - 1)
                        out[(size_t)NB * NT * (2 * NH) + (size_t)b * (2 * NH)
                            + dir * NH + j0 + jj] = h2;
                }
            }
        }
        __threadfence();
        grid.sync();
    }
}

extern "C" void kernel_launch(void* const* d_in, const int* in_sizes, int n_in,
                              void* d_out, int out_size, void* d_ws, size_t ws_size,
                              hipStream_t stream) {
    (void)in_sizes; (void)n_in; (void)out_size; (void)ws_size;
    const float* x     = (const float*)d_in[0];
    const int*   len   = (const int*)d_in[1];
    const float* fw_Wx = (const float*)d_in[2];
    const float* fw_Wh = (const float*)d_in[3];
    const float* fw_b  = (const float*)d_in[4];
    const float* bw_Wx = (const float*)d_in[5];
    const float* bw_Wh = (const float*)d_in[6];
    const float* bw_b  = (const float*)d_in[7];
    float* out = (float*)d_out;

    char* ws = (char*)d_ws;
    size_t off = 0;
    half_t* WT = (half_t*)(ws + off); off += (size_t)2048 * WREG * 2;   // 64 MB
    half_t* xh = (half_t*)(ws + off); off += XPLANE * 2;                // 32 MB
    half_t* xl = (half_t*)(ws + off); off += XPLANE * 2;                // 32 MB
    half_t* hbuf = (half_t*)(ws + off);                                 // 2 MB

    hipMemsetAsync(hbuf, 0, (size_t)4 * 2 * 2 * HPLANE * 2, stream);

    cvt_x<<<NB * NT, 256, 0, stream>>>(x, xh, xl);

    dim3 tg(G4 / 64, ND / 64, 8);
    transpose_pack<<<tg, 256, 0, stream>>>(fw_Wx, fw_Wh, bw_Wx, bw_Wh, WT);

    void* args[] = {(void*)&xh, (void*)&xl, (void*)&len, (void*)&fw_b,
                    (void*)&bw_b, (void*)&WT, (void*)&hbuf, (void*)&out};
    hipLaunchCooperativeKernel((void*)lstm_persistent, dim3(256), dim3(512),
                               args, 0, stream);
}

// Round 7
// 19092.477 us; speedup vs baseline: 1.7728x; 1.7728x over previous
//
#include <hip/hip_runtime.h>

#define NB 64
#define NT 256
#define ND 1024
#define NH 1024
#define G4 4096

typedef _Float16 half_t;
typedef half_t v8h __attribute__((ext_vector_type(8)));
typedef half_t h4  __attribute__((ext_vector_type(4)));
typedef float  v4f __attribute__((ext_vector_type(4)));

#define XPLANE ((size_t)NB * NT * ND)   // 16,777,216 elems per x plane
#define HPLANE ((size_t)NB * NH)        // 65,536 elems per h plane

// ---- one-time: x (B,T,D) f32 -> fp16 hi/lo planes, transposed to [t][b][d] ----
__global__ void cvt_x(const float* __restrict__ x,
                      half_t* __restrict__ xh, half_t* __restrict__ xl) {
    const int row = blockIdx.x;             // row = b*256 + t, 16384 rows
    const int b = row >> 8, t = row & 255;
    const int o = threadIdx.x * 4;          // 256 threads * 4 = 1024
    const float4 v = *(const float4*)(x + (size_t)row * ND + o);
    const size_t d = ((size_t)t * NB + b) * ND + o;
    h4 hh, ll;
    hh.x = (half_t)v.x; ll.x = (half_t)(v.x - (float)hh.x);
    hh.y = (half_t)v.y; ll.y = (half_t)(v.y - (float)hh.y);
    hh.z = (half_t)v.z; ll.z = (half_t)(v.z - (float)hh.z);
    hh.w = (half_t)v.w; ll.w = (half_t)(v.w - (float)hh.w);
    *(h4*)(xh + d) = hh;
    *(h4*)(xl + d) = ll;
}

// ---- one-time weight pack: fp16 ----
// region per (combo, jp, gt, q): [kiter 0..15][lane 0..63][8]  (8192 elems, 16 KB)
// combo: 0=fw L0, 1=bw L0, 2=fw L1, 3=bw L1;  k_global = [Wx 0..1023 | Wh 1024..2047]
__global__ void transpose_pack(const float* __restrict__ fw_Wx,
                               const float* __restrict__ fw_Wh,
                               const float* __restrict__ bw_Wx,
                               const float* __restrict__ bw_Wh,
                               half_t* __restrict__ WT) {
    const int z = blockIdx.z;
    const int combo = z >> 1;
    const int half  = z & 1;               // 0 -> Wx, 1 -> Wh
    const int layer = combo >> 1, dirb = combo & 1;
    const float* src = half ? (dirb ? bw_Wh : fw_Wh) : (dirb ? bw_Wx : fw_Wx);
    src += (size_t)layer * ND * G4;
    const int n0 = blockIdx.x * 64, k0 = blockIdx.y * 64;
    __shared__ float tile[64][65];
    const int t = threadIdx.x;             // 256 threads
    #pragma unroll
    for (int it = 0; it < 4; ++it) {
        const int kr = it * 16 + (t >> 4);
        const int nc = (t & 15) * 4;
        const float4 v = *(const float4*)(src + (size_t)(k0 + kr) * G4 + n0 + nc);
        tile[kr][nc + 0] = v.x; tile[kr][nc + 1] = v.y;
        tile[kr][nc + 2] = v.z; tile[kr][nc + 3] = v.w;
    }
    __syncthreads();
    #pragma unroll
    for (int it = 0; it < 4; ++it) {
        const int nr = it * 16 + (t >> 4);
        const int kc = (t & 15) * 4;       // k within 64-tile, multiple of 4
        h4 hv;
        hv.x = (half_t)tile[kc + 0][nr];
        hv.y = (half_t)tile[kc + 1][nr];
        hv.z = (half_t)tile[kc + 2][nr];
        hv.w = (half_t)tile[kc + 3][nr];
        const int n = n0 + nr;                 // 0..4095
        const int kg = half * 1024 + k0 + kc;  // 0..2047
        const int gt = n >> 10, j = n & 1023;
        const int jp = j >> 4, jl = j & 15;
        const int q = kg >> 9, kr2 = kg & 511;
        const int kit = kr2 >> 5, g2 = (kr2 >> 3) & 3, e0 = kr2 & 7;  // e0 in {0,4}
        const int lane2 = g2 * 16 + jl;
        const size_t r = (((size_t)combo * 64 + jp) * 4 + gt) * 4 + q;
        *(h4*)(WT + r * 8192 + (size_t)kit * 512 + lane2 * 8 + e0) = hv;
    }
}

// ---- per-direction inter-block barrier (128 blocks), monotonic, hand-rolled ----
__device__ __forceinline__ void dir_barrier(int* cnt, int* rel, int phase) {
    __syncthreads();                       // all block threads' stores drained to L2
    if (threadIdx.x == 0) {
        __threadfence();                   // release: L2 -> coherence point
        const int a = __hip_atomic_fetch_add(cnt, 1, __ATOMIC_RELAXED,
                                             __HIP_MEMORY_SCOPE_AGENT) + 1;
        if (a == phase * 128) {
            __hip_atomic_store(rel, phase, __ATOMIC_RELEASE, __HIP_MEMORY_SCOPE_AGENT);
        } else {
            while (__hip_atomic_load(rel, __ATOMIC_ACQUIRE,
                                     __HIP_MEMORY_SCOPE_AGENT) < phase)
                __builtin_amdgcn_s_sleep(2);
        }
        __threadfence();                   // acquire: invalidate stale lines
    }
    __syncthreads();
}

// ---- persistent scan: block=(combo, j-panel); 16 waves = (gate 4) x (K-quarter 4) ----
// hbuf layout: [combo][parity][plane hi/lo][B][H] fp16
__global__ __launch_bounds__(1024, 4) void lstm_persistent(
        const half_t* __restrict__ xh, const half_t* __restrict__ xl,
        const int* __restrict__ lengths,
        const float* __restrict__ fw_b, const float* __restrict__ bw_b,
        const half_t* __restrict__ WT,
        half_t* __restrict__ hbuf,
        float* __restrict__ out,
        int* __restrict__ bar) {
    const int c = blockIdx.x & 3, jp = blockIdx.x >> 2;
    const int layer = c >> 1, dir = c & 1;
    const int tid = threadIdx.x;
    const int wv = tid >> 6, lane = tid & 63;
    const int gt = wv & 3, q = wv >> 2;    // gate, K-quarter (512 wide)
    const int l15 = lane & 15, g = lane >> 4;
    const int j0 = jp * 16;

    __shared__ float glds[4][4][NB][16];   // [gate][q][batch][jj]  64 KB
    __shared__ float c_lds[NB][16];
    __shared__ float h_lds[NB][16];
    __shared__ float bias_lds[4][16];
    __shared__ int   len_lds[NB];

    for (int e = tid; e < NB * 16; e += 1024) {
        c_lds[e >> 4][e & 15] = 0.f;
        h_lds[e >> 4][e & 15] = 0.f;
    }
    if (tid < NB) len_lds[tid] = lengths[tid];
    if (tid < 64) {
        const int gg = tid >> 4, jj = tid & 15;
        const float* bs = dir ? bw_b : fw_b;
        bias_lds[gg][jj] = bs[(size_t)layer * G4 + gg * NH + j0 + jj];
    }

    // ---- W preload: this wave's 16 KB slice lives in 64 VGPRs for the whole scan ----
    v8h w[16];
    {
        const half_t* wp = WT + ((((size_t)c * 64 + jp) * 4 + gt) * 4 + q) * 8192
                         + (size_t)lane * 8;
        #pragma unroll
        for (int ki = 0; ki < 16; ++ki) w[ki] = *(const v8h*)(wp + (size_t)ki * 512);
        #pragma unroll
        for (int ki = 0; ki < 16; ++ki) asm volatile("" : "+v"(w[ki]));  // pin in regs
    }
    __syncthreads();

    int* mycnt = bar + dir * 32;
    int* myrel = bar + 64 + dir * 32;

    for (int s = 0; s <= NT; ++s) {
        const bool active = (layer == 0) ? (s < NT) : (s >= 1);
        const int u = (layer == 0) ? s : (s - 1);

        if (active) {
            // A source (fp16 hi/lo), rows = batch (stride 1024), cols = this q's 512 k
            const half_t *Ah, *Al;
            if (q < 2) {
                if (layer == 0) {
                    const int t = dir ? (NT - 1 - u) : u;
                    Ah = xh + (size_t)t * NB * ND + q * 512;
                    Al = xl + (size_t)t * NB * ND + q * 512;
                } else {
                    const half_t* hb = hbuf + (((size_t)dir * 2 + (s & 1)) * 2) * HPLANE;
                    Ah = hb + q * 512; Al = Ah + HPLANE;
                }
            } else {
                const half_t* hb = hbuf + (((size_t)c * 2 + (u & 1)) * 2) * HPLANE;
                Ah = hb + (q - 2) * 512; Al = Ah + HPLANE;
            }

            v4f acc0 = {0.f,0.f,0.f,0.f}, acc1 = acc0, acc2 = acc0, acc3 = acc0;
            #pragma unroll
            for (int ki = 0; ki < 16; ++ki) {
                const int co = ki * 32 + g * 8;
                v8h ah, al;
                ah = *(const v8h*)(Ah + (size_t)(l15     ) * 1024 + co);
                al = *(const v8h*)(Al + (size_t)(l15     ) * 1024 + co);
                acc0 = __builtin_amdgcn_mfma_f32_16x16x32_f16(ah, w[ki], acc0, 0, 0, 0);
                acc0 = __builtin_amdgcn_mfma_f32_16x16x32_f16(al, w[ki], acc0, 0, 0, 0);
                ah = *(const v8h*)(Ah + (size_t)(l15 + 16) * 1024 + co);
                al = *(const v8h*)(Al + (size_t)(l15 + 16) * 1024 + co);
                acc1 = __builtin_amdgcn_mfma_f32_16x16x32_f16(ah, w[ki], acc1, 0, 0, 0);
                acc1 = __builtin_amdgcn_mfma_f32_16x16x32_f16(al, w[ki], acc1, 0, 0, 0);
                ah = *(const v8h*)(Ah + (size_t)(l15 + 32) * 1024 + co);
                al = *(const v8h*)(Al + (size_t)(l15 + 32) * 1024 + co);
                acc2 = __builtin_amdgcn_mfma_f32_16x16x32_f16(ah, w[ki], acc2, 0, 0, 0);
                acc2 = __builtin_amdgcn_mfma_f32_16x16x32_f16(al, w[ki], acc2, 0, 0, 0);
                ah = *(const v8h*)(Ah + (size_t)(l15 + 48) * 1024 + co);
                al = *(const v8h*)(Al + (size_t)(l15 + 48) * 1024 + co);
                acc3 = __builtin_amdgcn_mfma_f32_16x16x32_f16(ah, w[ki], acc3, 0, 0, 0);
                acc3 = __builtin_amdgcn_mfma_f32_16x16x32_f16(al, w[ki], acc3, 0, 0, 0);
            }
            // C/D: col = l15 (jj), row-in-tile = g*4 + r (batch row)
            #pragma unroll
            for (int r = 0; r < 4; ++r) {
                glds[gt][q][ 0 + g * 4 + r][l15] = acc0[r];
                glds[gt][q][16 + g * 4 + r][l15] = acc1[r];
                glds[gt][q][32 + g * 4 + r][l15] = acc2[r];
                glds[gt][q][48 + g * 4 + r][l15] = acc3[r];
            }
        }
        __syncthreads();

        if (active) {
            // 1024 threads, 1024 elements: one (b, jj) each
            const int b = tid >> 4, jj = tid & 15;
            const float iv = glds[0][0][b][jj] + glds[0][1][b][jj]
                           + glds[0][2][b][jj] + glds[0][3][b][jj] + bias_lds[0][jj];
            const float fv = glds[1][0][b][jj] + glds[1][1][b][jj]
                           + glds[1][2][b][jj] + glds[1][3][b][jj] + bias_lds[1][jj];
            const float gv = glds[2][0][b][jj] + glds[2][1][b][jj]
                           + glds[2][2][b][jj] + glds[2][3][b][jj] + bias_lds[2][jj];
            const float ov = glds[3][0][b][jj] + glds[3][1][b][jj]
                           + glds[3][2][b][jj] + glds[3][3][b][jj] + bias_lds[3][jj];
            const float cold = c_lds[b][jj];
            const float hold = h_lds[b][jj];
            const float si = 1.f / (1.f + expf(-iv));
            const float sf = 1.f / (1.f + expf(-fv));
            const float so = 1.f / (1.f + expf(-ov));
            const float cn = sf * cold + si * tanhf(gv);
            const float hn = so * tanhf(cn);
            const bool valid = len_lds[b] > u;   // un-reversed mask (reference quirk)
            const float c2 = valid ? cn : cold;
            const float h2 = valid ? hn : hold;
            c_lds[b][jj] = c2;
            h_lds[b][jj] = h2;
            const size_t hb = (((size_t)c * 2 + ((u + 1) & 1)) * 2) * HPLANE
                            + (size_t)b * NH + j0 + jj;
            const half_t hh = (half_t)h2;
            hbuf[hb]          = hh;
            hbuf[hb + HPLANE] = (half_t)(h2 - (float)hh);
            if (layer == 1) {
                const int tout = dir ? (NT - 1 - u) : u;
                out[((size_t)b * NT + tout) * (2 * NH) + dir * NH + j0 + jj] = h2;
                if (u == NT - 1)
                    out[(size_t)NB * NT * (2 * NH) + (size_t)b * (2 * NH)
                        + dir * NH + j0 + jj] = h2;
            }
        }
        dir_barrier(mycnt, myrel, s + 1);
    }
}

extern "C" void kernel_launch(void* const* d_in, const int* in_sizes, int n_in,
                              void* d_out, int out_size, void* d_ws, size_t ws_size,
                              hipStream_t stream) {
    (void)in_sizes; (void)n_in; (void)out_size; (void)ws_size;
    const float* x     = (const float*)d_in[0];
    const int*   len   = (const int*)d_in[1];
    const float* fw_Wx = (const float*)d_in[2];
    const float* fw_Wh = (const float*)d_in[3];
    const float* fw_b  = (const float*)d_in[4];
    const float* bw_Wx = (const float*)d_in[5];
    const float* bw_Wh = (const float*)d_in[6];
    const float* bw_b  = (const float*)d_in[7];
    float* out = (float*)d_out;

    char* ws = (char*)d_ws;
    size_t off = 0;
    half_t* WT = (half_t*)(ws + off); off += (size_t)4096 * 8192 * 2;   // 64 MB
    half_t* xh = (half_t*)(ws + off); off += XPLANE * 2;                // 32 MB
    half_t* xl = (half_t*)(ws + off); off += XPLANE * 2;                // 32 MB
    half_t* hbuf = (half_t*)(ws + off); off += (size_t)4 * 2 * 2 * HPLANE * 2; // 2 MB
    int* bar = (int*)(ws + off);                                        // 512 B

    // zero h(0) state + barrier counters (contiguous)
    hipMemsetAsync(hbuf, 0, (size_t)4 * 2 * 2 * HPLANE * 2 + 512, stream);

    cvt_x<<<NB * NT, 256, 0, stream>>>(x, xh, xl);

    dim3 tg(G4 / 64, ND / 64, 8);
    transpose_pack<<<tg, 256, 0, stream>>>(fw_Wx, fw_Wh, bw_Wx, bw_Wh, WT);

    void* args[] = {(void*)&xh, (void*)&xl, (void*)&len, (void*)&fw_b,
                    (void*)&bw_b, (void*)&WT, (void*)&hbuf, (void*)&out,
                    (void*)&bar};
    hipLaunchCooperativeKernel((void*)lstm_persistent, dim3(256), dim3(1024),
                               args, 0, stream);
}